// Round 1
// baseline (362.473 us; speedup 1.0000x reference)
//
#include <hip/hip_runtime.h>

typedef __attribute__((ext_vector_type(8))) short s16x8;
typedef __attribute__((ext_vector_type(4))) float f32x4;
typedef unsigned short u16;
typedef unsigned int u32;

// ---------- helpers ----------
__device__ __forceinline__ u16 f2bf(float f) {            // RNE f32 -> bf16
  u32 u = __builtin_bit_cast(u32, f);
  u += 0x7fff + ((u >> 16) & 1);
  return (u16)(u >> 16);
}

__device__ __forceinline__ void gload16(const void* g, void* l) {
  // async global->LDS, 16B per lane; dest is wave-uniform base + lane*16
  __builtin_amdgcn_global_load_lds((const __attribute__((address_space(1))) u32*)g,
                                   (__attribute__((address_space(3))) u32*)l, 16, 0, 0);
}

#define MFMA(a, b, c) __builtin_amdgcn_mfma_f32_16x16x32_bf16((a), (b), (c), 0, 0, 0)

// ---------- fp32 -> bf16 convert (8 elems/thread) ----------
__global__ __launch_bounds__(256) void cvt_bf16(const float* __restrict__ src,
                                                u16* __restrict__ dst, int n8) {
  int i = blockIdx.x * 256 + threadIdx.x;
  if (i >= n8) return;
  const float4* s4 = (const float4*)src;
  float4 a = s4[2 * i], b = s4[2 * i + 1];
  uint4 o;
  o.x = (u32)f2bf(a.x) | ((u32)f2bf(a.y) << 16);
  o.y = (u32)f2bf(a.z) | ((u32)f2bf(a.w) << 16);
  o.z = (u32)f2bf(b.x) | ((u32)f2bf(b.y) << 16);
  o.w = (u32)f2bf(b.z) | ((u32)f2bf(b.w) << 16);
  ((uint4*)dst)[i] = o;
}

// ---------- W [1024][1024] f32 -> WT [1024][1024] bf16 ----------
__global__ __launch_bounds__(256) void transpose_w_k(const float* __restrict__ W,
                                                     u16* __restrict__ WT) {
  __shared__ float t[32][33];
  int tx = threadIdx.x, ty = threadIdx.y;
  int n = blockIdx.x * 32 + tx;
#pragma unroll
  for (int j = 0; j < 4; j++) {
    int k = blockIdx.y * 32 + ty + 8 * j;
    t[ty + 8 * j][tx] = W[(size_t)k * 1024 + n];
  }
  __syncthreads();
  int k = blockIdx.y * 32 + tx;
#pragma unroll
  for (int j = 0; j < 4; j++) {
    int n2 = blockIdx.x * 32 + ty + 8 * j;
    WT[(size_t)n2 * 1024 + k] = f2bf(t[tx][ty + 8 * j]);
  }
}

// ---------- shared GEMM core: C[BMxBN] = A[m0..][K=1024] * BT[n0..][K=1024]^T ----------
template <int BM, int BN>
__device__ __forceinline__ void gemm_core(const u16* __restrict__ A, const u16* __restrict__ BT,
                                          int m0, int n0, u16* Ash, u16* Bsh,
                                          f32x4 (&acc)[BM / 32][BN / 32]) {
  constexpr int MF = BM / 32, NF = BN / 32;
  const int tid = threadIdx.x;
  const int lane = tid & 63, wid = tid >> 6;
  const int r16 = lane & 15, g = lane >> 4;
  const int wm = wid >> 1, wn = wid & 1;
  const f32x4 vz = {0.f, 0.f, 0.f, 0.f};
#pragma unroll
  for (int mf = 0; mf < MF; mf++)
#pragma unroll
    for (int nf = 0; nf < NF; nf++) acc[mf][nf] = vz;

  for (int k0 = 0; k0 < 1024; k0 += 64) {
#pragma unroll
    for (int i = 0; i < BM / 32; i++) {  // A tile: BM x 64 bf16, 16B chunks
      int ch = i * 256 + tid;
      gload16((const char*)A + (((size_t)(m0 + (ch >> 3)) << 10) + k0 + ((ch & 7) << 3)) * 2,
              (char*)Ash + ch * 16);
    }
#pragma unroll
    for (int i = 0; i < BN / 32; i++) {  // BT tile: BN x 64 bf16
      int ch = i * 256 + tid;
      gload16((const char*)BT + (((size_t)(n0 + (ch >> 3)) << 10) + k0 + ((ch & 7) << 3)) * 2,
              (char*)Bsh + ch * 16);
    }
    __syncthreads();
#pragma unroll
    for (int kk = 0; kk < 2; kk++) {
      s16x8 af[MF], bfr[NF];
#pragma unroll
      for (int mf = 0; mf < MF; mf++)
        af[mf] = *(const s16x8*)(Ash + ((wm * (BM / 2) + mf * 16 + r16) << 6) + kk * 32 + g * 8);
#pragma unroll
      for (int nf = 0; nf < NF; nf++)
        bfr[nf] = *(const s16x8*)(Bsh + ((wn * (BN / 2) + nf * 16 + r16) << 6) + kk * 32 + g * 8);
#pragma unroll
      for (int mf = 0; mf < MF; mf++)
#pragma unroll
        for (int nf = 0; nf < NF; nf++) acc[mf][nf] = MFMA(af[mf], bfr[nf], acc[mf][nf]);
    }
    __syncthreads();
  }
}

// ---------- fused QKV projection: z=0 Q, z=1 K (head-major), z=2 V (transposed) ----------
__global__ __launch_bounds__(256) void proj_gemm(
    const u16* __restrict__ Xq, const u16* __restrict__ Xk, const u16* __restrict__ Xv,
    const u16* __restrict__ WqT, const u16* __restrict__ WkT, const u16* __restrict__ WvT,
    const float* __restrict__ bq, const float* __restrict__ bk, const float* __restrict__ bv,
    u16* __restrict__ Qo, u16* __restrict__ Ko, u16* __restrict__ Vto) {
  __shared__ u16 Ash[128 * 64], Bsh[128 * 64];
  const int z = blockIdx.z;
  const u16* A = (z == 0) ? Xq : (z == 1) ? Xk : Xv;
  const u16* BT = (z == 0) ? WqT : (z == 1) ? WkT : WvT;
  const float* bias = (z == 0) ? bq : (z == 1) ? bk : bv;
  u16* O = (z == 0) ? Qo : (z == 1) ? Ko : Vto;
  const int m0 = blockIdx.y * 128, n0 = blockIdx.x * 128;
  f32x4 acc[4][4];
  gemm_core<128, 128>(A, BT, m0, n0, Ash, Bsh, acc);
  const int tid = threadIdx.x, lane = tid & 63, wid = tid >> 6;
  const int r16 = lane & 15, g = lane >> 4, wm = wid >> 1, wn = wid & 1;
#pragma unroll
  for (int nf = 0; nf < 4; nf++) {
    int col = n0 + wn * 64 + nf * 16 + r16;
    float bb = bias[col];
    int h = col >> 6, d = col & 63;
#pragma unroll
    for (int mf = 0; mf < 4; mf++) {
#pragma unroll
      for (int ri = 0; ri < 4; ri++) {
        int row = m0 + wm * 64 + mf * 16 + g * 4 + ri;
        int b_ = row >> 11, s_ = row & 2047;
        u16 val = f2bf(acc[mf][nf][ri] + bb);
        if (z < 2)
          O[((((size_t)b_ * 16 + h) * 2048 + s_) << 6) + d] = val;     // [B,H,S,64]
        else
          O[((((size_t)b_ * 16 + h) * 64 + d) << 11) + s_] = val;     // [B,H,64,S]
      }
    }
  }
}

// ---------- output projection: out = ctx @ WoT^T + bo (fp32) ----------
__global__ __launch_bounds__(256) void out_gemm(const u16* __restrict__ ctx,
                                                const u16* __restrict__ WoT,
                                                const float* __restrict__ bo,
                                                float* __restrict__ out) {
  __shared__ u16 Ash[64 * 64], Bsh[128 * 64];
  const int m0 = blockIdx.y * 64, n0 = blockIdx.x * 128;
  f32x4 acc[2][4];
  gemm_core<64, 128>(ctx, WoT, m0, n0, Ash, Bsh, acc);
  const int tid = threadIdx.x, lane = tid & 63, wid = tid >> 6;
  const int r16 = lane & 15, g = lane >> 4, wm = wid >> 1, wn = wid & 1;
#pragma unroll
  for (int nf = 0; nf < 4; nf++) {
    int col = n0 + wn * 64 + nf * 16 + r16;
    float bb = bo[col];
#pragma unroll
    for (int mf = 0; mf < 2; mf++) {
#pragma unroll
      for (int ri = 0; ri < 4; ri++) {
        int row = m0 + wm * 32 + mf * 16 + g * 4 + ri;
        out[((size_t)row << 10) + col] = acc[mf][nf][ri] + bb;
      }
    }
  }
}

// ---------- flash attention: block = (q-tile 64, h, b), 4 waves x 16 q-rows ----------
__global__ __launch_bounds__(256) void flash_attn(const u16* __restrict__ Q,
                                                  const u16* __restrict__ K,
                                                  const u16* __restrict__ Vt,
                                                  const int* __restrict__ mask,
                                                  u16* __restrict__ ctx) {
  __shared__ __align__(16) u16 P[4][16][80];  // per-wave P tile, stride 80 kills 16-way conflict
  const int tid = threadIdx.x, w = tid >> 6, lane = tid & 63;
  const int r16 = lane & 15, g = lane >> 4;
  const int b = blockIdx.z, h = blockIdx.y;
  const int q0 = blockIdx.x * 64 + w * 16;
  const u16* Qb = Q + ((size_t)(b * 16 + h) << 17);
  const u16* Kb = K + ((size_t)(b * 16 + h) << 17);
  const u16* Vb = Vt + ((size_t)(b * 16 + h) << 17);
  const int* Mb = mask + ((size_t)b << 22);

  s16x8 aq[2];
#pragma unroll
  for (int c = 0; c < 2; c++) aq[c] = *(const s16x8*)(Qb + ((q0 + r16) << 6) + c * 32 + g * 8);

  const f32x4 vz = {0.f, 0.f, 0.f, 0.f};
  f32x4 o[4];
  float mrun[4], lrun[4];
#pragma unroll
  for (int i = 0; i < 4; i++) { o[i] = vz; mrun[i] = -1e30f; lrun[i] = 0.f; }

  for (int kv0 = 0; kv0 < 2048; kv0 += 64) {
    f32x4 s[4];
#pragma unroll
    for (int nt = 0; nt < 4; nt++) s[nt] = vz;
#pragma unroll
    for (int c = 0; c < 2; c++) {
#pragma unroll
      for (int nt = 0; nt < 4; nt++) {
        s16x8 bk = *(const s16x8*)(Kb + ((kv0 + nt * 16 + r16) << 6) + c * 32 + g * 8);
        s[nt] = MFMA(aq[c], bk, s[nt]);
      }
    }
    // scale + mask + row max
    float p[4][4], pm[4];
#pragma unroll
    for (int ri = 0; ri < 4; ri++) pm[ri] = -1e30f;
    const int qr = q0 + g * 4;
#pragma unroll
    for (int nt = 0; nt < 4; nt++) {
      int kc = kv0 + nt * 16 + r16;
#pragma unroll
      for (int ri = 0; ri < 4; ri++) {
        float v = s[nt][ri] * 0.125f;
        if (Mb[((size_t)(qr + ri) << 11) + kc] == 0) v = -1e9f;
        p[nt][ri] = v;
        pm[ri] = fmaxf(pm[ri], v);
      }
    }
#pragma unroll
    for (int ri = 0; ri < 4; ri++)
#pragma unroll
      for (int mm = 1; mm < 16; mm <<= 1) pm[ri] = fmaxf(pm[ri], __shfl_xor(pm[ri], mm, 64));
    // online softmax update
    float alpha[4];
#pragma unroll
    for (int ri = 0; ri < 4; ri++) {
      float mn = fmaxf(mrun[ri], pm[ri]);
      alpha[ri] = __expf(mrun[ri] - mn);
      mrun[ri] = mn;
    }
    float rs[4] = {0.f, 0.f, 0.f, 0.f};
#pragma unroll
    for (int nt = 0; nt < 4; nt++)
#pragma unroll
      for (int ri = 0; ri < 4; ri++) {
        float e = __expf(p[nt][ri] - mrun[ri]);
        p[nt][ri] = e;
        rs[ri] += e;
      }
#pragma unroll
    for (int ri = 0; ri < 4; ri++) {
#pragma unroll
      for (int mm = 1; mm < 16; mm <<= 1) rs[ri] += __shfl_xor(rs[ri], mm, 64);
      lrun[ri] = lrun[ri] * alpha[ri] + rs[ri];
    }
#pragma unroll
    for (int nt = 0; nt < 4; nt++)
#pragma unroll
      for (int ri = 0; ri < 4; ri++) o[nt][ri] *= alpha[ri];
    // P (C-layout) -> LDS -> A-fragment layout
#pragma unroll
    for (int nt = 0; nt < 4; nt++)
#pragma unroll
      for (int ri = 0; ri < 4; ri++) P[w][g * 4 + ri][nt * 16 + r16] = f2bf(p[nt][ri]);
    asm volatile("" ::: "memory");  // keep ds_write before ds_read (same-wave in-order LDS)
#pragma unroll
    for (int c = 0; c < 2; c++) {
      s16x8 pa = *(const s16x8*)(&P[w][r16][c * 32 + g * 8]);
#pragma unroll
      for (int nt = 0; nt < 4; nt++) {
        s16x8 bv = *(const s16x8*)(Vb + ((size_t)(nt * 16 + r16) << 11) + kv0 + c * 32 + g * 8);
        o[nt] = MFMA(pa, bv, o[nt]);
      }
    }
    asm volatile("" ::: "memory");
  }
  // normalize + write ctx bf16 [B*S][1024]
  float inv[4];
#pragma unroll
  for (int ri = 0; ri < 4; ri++) inv[ri] = 1.f / lrun[ri];
#pragma unroll
  for (int nt = 0; nt < 4; nt++) {
    int col = (h << 6) + nt * 16 + r16;
#pragma unroll
    for (int ri = 0; ri < 4; ri++) {
      int row = (b << 11) + q0 + g * 4 + ri;
      ctx[((size_t)row << 10) + col] = f2bf(o[nt][ri] * inv[ri]);
    }
  }
}

// ---------- host ----------
extern "C" void kernel_launch(void* const* d_in, const int* in_sizes, int n_in,
                              void* d_out, int out_size, void* d_ws, size_t ws_size,
                              hipStream_t stream) {
  const float* query = (const float*)d_in[0];
  const float* key_  = (const float*)d_in[1];
  const float* value = (const float*)d_in[2];
  const int*   mask  = (const int*)d_in[3];
  const float* Wq = (const float*)d_in[4];
  const float* bq = (const float*)d_in[5];
  const float* Wk = (const float*)d_in[6];
  const float* bk = (const float*)d_in[7];
  const float* Wv = (const float*)d_in[8];
  const float* bv = (const float*)d_in[9];
  const float* Wo = (const float*)d_in[10];
  const float* bo = (const float*)d_in[11];

  const size_t MB = 1048576;
  char* ws = (char*)d_ws;
  u16* Xq  = (u16*)(ws + 0 * MB);
  u16* Xk  = (u16*)(ws + 8 * MB);
  u16* Xv  = (u16*)(ws + 16 * MB);
  u16* WqT = (u16*)(ws + 24 * MB);
  u16* WkT = (u16*)(ws + 26 * MB);
  u16* WvT = (u16*)(ws + 28 * MB);
  u16* WoT = (u16*)(ws + 30 * MB);
  u16* Qd  = (u16*)(ws + 32 * MB);
  u16* Kd  = (u16*)(ws + 40 * MB);
  u16* Vtd = (u16*)(ws + 48 * MB);
  u16* ctx = (u16*)(ws + 56 * MB);

  cvt_bf16<<<2048, 256, 0, stream>>>(query, Xq, 524288);
  cvt_bf16<<<2048, 256, 0, stream>>>(key_,  Xk, 524288);
  cvt_bf16<<<2048, 256, 0, stream>>>(value, Xv, 524288);

  dim3 tb(32, 8);
  transpose_w_k<<<dim3(32, 32), tb, 0, stream>>>(Wq, WqT);
  transpose_w_k<<<dim3(32, 32), tb, 0, stream>>>(Wk, WkT);
  transpose_w_k<<<dim3(32, 32), tb, 0, stream>>>(Wv, WvT);
  transpose_w_k<<<dim3(32, 32), tb, 0, stream>>>(Wo, WoT);

  proj_gemm<<<dim3(8, 32, 3), 256, 0, stream>>>(Xq, Xk, Xv, WqT, WkT, WvT, bq, bk, bv,
                                                Qd, Kd, Vtd);
  flash_attn<<<dim3(32, 16, 2), 256, 0, stream>>>(Qd, Kd, Vtd, mask, ctx);
  out_gemm<<<dim3(8, 64), 256, 0, stream>>>(ctx, WoT, bo, (float*)d_out);
}